// Round 1
// baseline (6189.465 us; speedup 1.0000x reference)
//
#include <hip/hip_runtime.h>

typedef _Float16 f16;
typedef _Float16 f16x8 __attribute__((ext_vector_type(8)));
typedef float f32x16 __attribute__((ext_vector_type(16)));
typedef unsigned short u16;
typedef unsigned int u32;

#define NSAMP 131072
#define HID 512
#define BW 2   // waves per block; each wave owns 32 samples + 32KB private LDS

// activation width after layer l (l = 0..6) for factor f
__host__ __device__ constexpr int wact(int f, int l) {
    if (f == 0) return 256;
    if (f == 2) return 512;
    return (l & 1) ? 256 : 512;   // factor 1: 512,256,512,...
}
// weight tiles (1KB = 32x16 fp16 A-fragment tile) per (factor, layer 0..7)
__host__ __device__ constexpr int seg_tiles(int f, int l) {
    if (l == 0) return wact(f, 0) / 32;                   // KT=1 (K: 6 padded to 16)
    if (l == 7) return wact(f, 6) / 16;                   // FT=1 (rows: 3 padded to 32)
    return (wact(f, l) / 32) * (wact(f, l - 1) / 16);     // FT*KT
}
__host__ __device__ constexpr int seg_off(int f, int l) {
    int o = 0;
    for (int ff = 0; ff < 3; ++ff)
        for (int ll = 0; ll < 8; ++ll) {
            if (ff == f && ll == l) return o;
            o += seg_tiles(ff, ll);
        }
    return o;
}
constexpr int TOTAL_TILES = seg_off(2, 7) + seg_tiles(2, 7);   // 5496 tiles -> 5.5MB in d_ws

// ---------------- prep: convert + tile all weights to fp16 A-fragment layout ----------------
// tile t = kt*FT + ft; element e = lane*8 + j holds W[ft*32 + (lane&31)][kt*16 + (lane>>5)*8 + j]
__global__ __launch_bounds__(256) void prep_kernel(const float* __restrict__ W_in,
                                                   const float* __restrict__ Ws,
                                                   const float* __restrict__ W_out,
                                                   u16* __restrict__ wt) {
    int b = blockIdx.x;
    int f = 0, l = 0, start = 0;
    for (int s = 0; s < 24; ++s) {
        int ff = s >> 3, ll = s & 7;
        int t = seg_tiles(ff, ll);
        if (b < start + t) { f = ff; l = ll; break; }
        start += t;
    }
    int lt = b - start;
    int FT = (l == 7) ? 1 : wact(f, l) / 32;
    int sh = (FT == 16) ? 4 : (FT == 8) ? 3 : 0;
    int kt = lt >> sh;
    int ft = lt & (FT - 1);
    const float* src; int stride, vr, vc;
    if (l == 0)      { src = W_in;                     stride = 6;   vr = 512; vc = 6;   }
    else if (l == 7) { src = W_out;                    stride = HID; vr = 3;   vc = HID; }
    else             { src = Ws + (l - 1) * HID * HID; stride = HID; vr = HID; vc = HID; }
    u16* dst = wt + (size_t)b * 512;
    #pragma unroll
    for (int t = 0; t < 2; ++t) {
        int e = threadIdx.x * 2 + t;
        int lane = e >> 3, j = e & 7;
        int row = ft * 32 + (lane & 31);
        int col = kt * 16 + (lane >> 5) * 8 + j;
        float v = (row < vr && col < vc) ? src[row * stride + col] : 0.0f;
        dst[e] = __builtin_bit_cast(u16, (f16)v);
    }
}

// ---------------- main fused kernel ----------------
__device__ __forceinline__ f32x16 zero16() {
    f32x16 z = {0.f,0.f,0.f,0.f,0.f,0.f,0.f,0.f,0.f,0.f,0.f,0.f,0.f,0.f,0.f,0.f};
    return z;
}

// bias + LN stats + LN apply + relu + fp16 pack + swizzled LDS write.
// D layout (32x32): col = sample = lane&31, row(feat-local) = (reg&3) + 8*(reg>>2) + 4*(lane>>5)
template<int FT>
__device__ __forceinline__ void epilogue(f32x16 (&acc)[FT],
                                         const float* __restrict__ bias,
                                         const float* __restrict__ lw,
                                         const float* __restrict__ lb,
                                         char* lds, int sl, int h, int swz) {
    constexpr float invD = 1.0f / (FT * 32);
    float s = 0.f, ss = 0.f;
    #pragma unroll
    for (int ft = 0; ft < FT; ++ft) {
        #pragma unroll
        for (int q = 0; q < 4; ++q) {
            float4 bv = *reinterpret_cast<const float4*>(bias + ft*32 + q*8 + h*4);
            #pragma unroll
            for (int r = 0; r < 4; ++r) {
                float v = acc[ft][q*4+r] + (&bv.x)[r];
                acc[ft][q*4+r] = v;
                s += v; ss += v*v;
            }
        }
    }
    // full 512(or 256)-feat row lives on lanes l and l^32 (same sample column)
    s  += __shfl_xor(s, 32);
    ss += __shfl_xor(ss, 32);
    float mean = s * invD;
    float var  = ss * invD - mean * mean;
    float rstd = 1.0f / sqrtf(var + 1e-5f);
    #pragma unroll
    for (int ft = 0; ft < FT; ++ft) {
        #pragma unroll
        for (int q = 0; q < 4; ++q) {
            float4 wv  = *reinterpret_cast<const float4*>(lw + ft*32 + q*8 + h*4);
            float4 lbv = *reinterpret_cast<const float4*>(lb + ft*32 + q*8 + h*4);
            float o[4];
            #pragma unroll
            for (int r = 0; r < 4; ++r) {
                float xn = (acc[ft][q*4+r] - mean) * rstd;
                float y  = (&wv.x)[r] * xn + (&lbv.x)[r];
                o[r] = fmaxf(y, 0.0f);
            }
            u32 p0 = (u32)__builtin_bit_cast(u16, (f16)o[0]) | ((u32)__builtin_bit_cast(u16, (f16)o[1]) << 16);
            u32 p1 = (u32)__builtin_bit_cast(u16, (f16)o[2]) | ((u32)__builtin_bit_cast(u16, (f16)o[3]) << 16);
            // act[samp sl][feat 32ft+8q+4h .. +3], 16B-granule XOR swizzle vs bank conflicts
            int byte = sl*1024 + ((ft*64 + q*16 + h*8) ^ swz);
            *reinterpret_cast<uint2*>(lds + byte) = make_uint2(p0, p1);
        }
    }
}

template<int DIN, int DOUT>
__device__ __forceinline__ void hidden_layer(const u16* __restrict__ wt,
                                             const float* __restrict__ bias,
                                             const float* __restrict__ lw,
                                             const float* __restrict__ lb,
                                             char* lds, int lane, int sl, int h, int swz) {
    constexpr int KT = DIN / 16, FT = DOUT / 32;
    f32x16 acc[FT];
    #pragma unroll
    for (int ft = 0; ft < FT; ++ft) acc[ft] = zero16();
    const u16* wl = wt + lane * 8;
    #pragma unroll 2
    for (int kt = 0; kt < KT; ++kt) {
        // B frag: x[k = kt*16 + 8h + j][samp sl] -> 16B swizzled ds_read_b128
        uint4 braw = *reinterpret_cast<const uint4*>(lds + sl*1024 + ((kt*32 + h*16) ^ swz));
        f16x8 B = __builtin_bit_cast(f16x8, braw);
        const u16* wk = wl + kt * (FT * 512);
        #pragma unroll
        for (int ft = 0; ft < FT; ++ft) {
            f16x8 A = *reinterpret_cast<const f16x8*>(wk + ft * 512);
            acc[ft] = __builtin_amdgcn_mfma_f32_32x32x16_f16(A, B, acc[ft], 0, 0, 0);
        }
    }
    epilogue<FT>(acc, bias, lw, lb, lds, sl, h, swz);
}

template<int DOUT>
__device__ __forceinline__ void lin_in_layer(const float* __restrict__ inp,
                                             const u16* __restrict__ wt,
                                             const float* __restrict__ bias,
                                             const float* __restrict__ lw,
                                             const float* __restrict__ lb,
                                             char* lds, int samp, int lane, int sl, int h, int swz) {
    constexpr int FT = DOUT / 32;
    float2 v0 = *reinterpret_cast<const float2*>(inp + (size_t)samp * 6 + 0);
    float2 v1 = *reinterpret_cast<const float2*>(inp + (size_t)samp * 6 + 2);
    float2 v2 = *reinterpret_cast<const float2*>(inp + (size_t)samp * 6 + 4);
    bool lo = (h == 0);
    f16x8 B;
    B[0] = lo ? (f16)v0.x : (f16)0.f;
    B[1] = lo ? (f16)v0.y : (f16)0.f;
    B[2] = lo ? (f16)v1.x : (f16)0.f;
    B[3] = lo ? (f16)v1.y : (f16)0.f;
    B[4] = lo ? (f16)v2.x : (f16)0.f;
    B[5] = lo ? (f16)v2.y : (f16)0.f;
    B[6] = (f16)0.f;
    B[7] = (f16)0.f;
    f32x16 acc[FT];
    #pragma unroll
    for (int ft = 0; ft < FT; ++ft) acc[ft] = zero16();
    const u16* wl = wt + lane * 8;
    #pragma unroll
    for (int ft = 0; ft < FT; ++ft) {
        f16x8 A = *reinterpret_cast<const f16x8*>(wl + ft * 512);
        acc[ft] = __builtin_amdgcn_mfma_f32_32x32x16_f16(A, B, acc[ft], 0, 0, 0);
    }
    epilogue<FT>(acc, bias, lw, lb, lds, sl, h, swz);
}

template<int DIN>
__device__ __forceinline__ void lin_out_layer(const u16* __restrict__ wt,
                                              const float* __restrict__ b_out,
                                              char* lds, float* __restrict__ out,
                                              int samp, int fidx, int lane, int sl, int h, int swz) {
    constexpr int KT = DIN / 16;
    f32x16 acc = zero16();
    const u16* wl = wt + lane * 8;
    #pragma unroll 2
    for (int kt = 0; kt < KT; ++kt) {
        uint4 braw = *reinterpret_cast<const uint4*>(lds + sl*1024 + ((kt*32 + h*16) ^ swz));
        f16x8 B = __builtin_bit_cast(f16x8, braw);
        f16x8 A = *reinterpret_cast<const f16x8*>(wl + kt * 512);
        acc = __builtin_amdgcn_mfma_f32_32x32x16_f16(A, B, acc, 0, 0, 0);
    }
    if (h == 0) {   // rows 0..2 of D live in regs 0..2 of the low half
        float* o = out + (size_t)samp * 9 + fidx * 3;
        o[0] = acc[0] + b_out[0];
        o[1] = acc[1] + b_out[1];
        o[2] = acc[2] + b_out[2];
    }
}

template<int F>
__device__ __forceinline__ void run_factor(const float* inp, const float* b_in, const float* bs,
                                           const float* lnw, const float* lnb, const float* b_out,
                                           const u16* wt, float* out,
                                           char* lds, int samp, int lane, int sl, int h, int swz) {
    lin_in_layer<wact(F,0)>(inp, wt + (size_t)seg_off(F,0)*512, b_in, lnw, lnb, lds, samp, lane, sl, h, swz);
    __syncthreads();
    hidden_layer<wact(F,0), wact(F,1)>(wt + (size_t)seg_off(F,1)*512, bs + 0*HID, lnw + 1*HID, lnb + 1*HID, lds, lane, sl, h, swz);
    __syncthreads();
    hidden_layer<wact(F,1), wact(F,2)>(wt + (size_t)seg_off(F,2)*512, bs + 1*HID, lnw + 2*HID, lnb + 2*HID, lds, lane, sl, h, swz);
    __syncthreads();
    hidden_layer<wact(F,2), wact(F,3)>(wt + (size_t)seg_off(F,3)*512, bs + 2*HID, lnw + 3*HID, lnb + 3*HID, lds, lane, sl, h, swz);
    __syncthreads();
    hidden_layer<wact(F,3), wact(F,4)>(wt + (size_t)seg_off(F,4)*512, bs + 3*HID, lnw + 4*HID, lnb + 4*HID, lds, lane, sl, h, swz);
    __syncthreads();
    hidden_layer<wact(F,4), wact(F,5)>(wt + (size_t)seg_off(F,5)*512, bs + 4*HID, lnw + 5*HID, lnb + 5*HID, lds, lane, sl, h, swz);
    __syncthreads();
    hidden_layer<wact(F,5), wact(F,6)>(wt + (size_t)seg_off(F,6)*512, bs + 5*HID, lnw + 6*HID, lnb + 6*HID, lds, lane, sl, h, swz);
    __syncthreads();
    lin_out_layer<wact(F,6)>(wt + (size_t)seg_off(F,7)*512, b_out, lds, out, samp, F, lane, sl, h, swz);
    __syncthreads();
}

__global__ __launch_bounds__(BW*64, 1) void mipnet_kernel(
        const float* __restrict__ inp, const float* __restrict__ b_in,
        const float* __restrict__ bs, const float* __restrict__ lnw,
        const float* __restrict__ lnb, const float* __restrict__ b_out,
        const u16* __restrict__ wt, float* __restrict__ out) {
    extern __shared__ char lds_all[];
    int tid  = threadIdx.x;
    int wave = tid >> 6;
    int lane = tid & 63;
    int h    = lane >> 5;     // lane half: selects k-subrange / feat quad half
    int sl   = lane & 31;     // sample within wave tile
    char* lds = lds_all + wave * 32768;     // wave-private activation buffer [32 samp][512 feat] fp16
    int samp = (blockIdx.x * BW + wave) * 32 + sl;
    int swz  = (sl & 15) << 4;              // 16B-granule XOR swizzle
    run_factor<0>(inp, b_in, bs, lnw, lnb, b_out, wt, out, lds, samp, lane, sl, h, swz);
    run_factor<1>(inp, b_in, bs, lnw, lnb, b_out, wt, out, lds, samp, lane, sl, h, swz);
    run_factor<2>(inp, b_in, bs, lnw, lnb, b_out, wt, out, lds, samp, lane, sl, h, swz);
}

extern "C" void kernel_launch(void* const* d_in, const int* in_sizes, int n_in,
                              void* d_out, int out_size, void* d_ws, size_t ws_size,
                              hipStream_t stream) {
    (void)in_sizes; (void)n_in; (void)out_size; (void)ws_size;
    const float* inputs = (const float*)d_in[0];
    const float* W_in   = (const float*)d_in[1];
    const float* b_in   = (const float*)d_in[2];
    const float* Ws     = (const float*)d_in[3];
    const float* bs     = (const float*)d_in[4];
    const float* lnw    = (const float*)d_in[5];
    const float* lnb    = (const float*)d_in[6];
    const float* W_out  = (const float*)d_in[7];
    const float* b_out  = (const float*)d_in[8];
    u16* wt = (u16*)d_ws;   // needs TOTAL_TILES*1024 = ~5.5MB of scratch

    prep_kernel<<<TOTAL_TILES, 256, 0, stream>>>(W_in, Ws, W_out, wt);
    mipnet_kernel<<<NSAMP/(32*BW), BW*64, BW*32768, stream>>>(
        inputs, b_in, bs, lnw, lnb, b_out, wt, (float*)d_out);
}

// Round 2
// 2038.252 us; speedup vs baseline: 3.0367x; 3.0367x over previous
//
#include <hip/hip_runtime.h>

typedef _Float16 f16;
typedef _Float16 f16x8 __attribute__((ext_vector_type(8)));
typedef float f32x16 __attribute__((ext_vector_type(16)));
typedef unsigned short u16;
typedef unsigned int u32;

#define NSAMP 131072
#define HID 512
#define NW 4              // waves per block
#define BSAMP 64          // samples per block (2 sample-tiles of 32, shared by all waves)

// LDS map: two 64KB act buffers (ping-pong) + cross-wave LN stats
#define LDSB   (64 * 1024)
#define STATS_OFF (2 * LDSB)
#define LDS_TOTAL (2 * LDSB + NW * BSAMP * 8)

// activation width after layer l (l = 0..6) for factor f
__host__ __device__ constexpr int wact(int f, int l) {
    if (f == 0) return 256;
    if (f == 2) return 512;
    return (l & 1) ? 256 : 512;   // factor 1: 512,256,512,...
}
// weight tiles (1KB = 32x16 fp16 A-fragment tile) per (factor, layer 0..7)
__host__ __device__ constexpr int seg_tiles(int f, int l) {
    if (l == 0) return wact(f, 0) / 32;                   // KT=1 (K: 6 padded to 16)
    if (l == 7) return wact(f, 6) / 16;                   // FT=1 (rows: 3 padded to 32)
    return (wact(f, l) / 32) * (wact(f, l - 1) / 16);     // FT*KT
}
__host__ __device__ constexpr int seg_off(int f, int l) {
    int o = 0;
    for (int ff = 0; ff < 3; ++ff)
        for (int ll = 0; ll < 8; ++ll) {
            if (ff == f && ll == l) return o;
            o += seg_tiles(ff, ll);
        }
    return o;
}
constexpr int TOTAL_TILES = seg_off(2, 7) + seg_tiles(2, 7);   // 5496 tiles -> 5.5MB in d_ws

// ---------------- prep: convert + tile all weights to fp16 A-fragment layout ----------------
// tile t = kt*FT + ft; element e = lane*8 + j holds W[ft*32 + (lane&31)][kt*16 + (lane>>5)*8 + j]
__global__ __launch_bounds__(256) void prep_kernel(const float* __restrict__ W_in,
                                                   const float* __restrict__ Ws,
                                                   const float* __restrict__ W_out,
                                                   u16* __restrict__ wt) {
    int b = blockIdx.x;
    int f = 0, l = 0, start = 0;
    for (int s = 0; s < 24; ++s) {
        int ff = s >> 3, ll = s & 7;
        int t = seg_tiles(ff, ll);
        if (b < start + t) { f = ff; l = ll; break; }
        start += t;
    }
    int lt = b - start;
    int FT = (l == 7) ? 1 : wact(f, l) / 32;
    int sh = (FT == 16) ? 4 : (FT == 8) ? 3 : 0;
    int kt = lt >> sh;
    int ft = lt & (FT - 1);
    const float* src; int stride, vr, vc;
    if (l == 0)      { src = W_in;                     stride = 6;   vr = 512; vc = 6;   }
    else if (l == 7) { src = W_out;                    stride = HID; vr = 3;   vc = HID; }
    else             { src = Ws + (l - 1) * HID * HID; stride = HID; vr = HID; vc = HID; }
    u16* dst = wt + (size_t)b * 512;
    #pragma unroll
    for (int t = 0; t < 2; ++t) {
        int e = threadIdx.x * 2 + t;
        int lane = e >> 3, j = e & 7;
        int row = ft * 32 + (lane & 31);
        int col = kt * 16 + (lane >> 5) * 8 + j;
        float v = (row < vr && col < vc) ? src[row * stride + col] : 0.0f;
        dst[e] = __builtin_bit_cast(u16, (f16)v);
    }
}

// ---------------- main fused kernel helpers ----------------
__device__ __forceinline__ f32x16 zero16() {
    f32x16 z = {0.f,0.f,0.f,0.f,0.f,0.f,0.f,0.f,0.f,0.f,0.f,0.f,0.f,0.f,0.f,0.f};
    return z;
}
__device__ __forceinline__ f16x8 bc(const uint4 v) { return __builtin_bit_cast(f16x8, v); }

// pass1: bias add, partial LN stats, fp16 pack, swizzled LDS write of pre-LN act.
// D layout (32x32): col(sample) = lane&31, row(feat-local) = (r&3) + 8*(r>>2) + 4*h
template<int FW>
__device__ __forceinline__ void pass1(f32x16 (&acc)[FW][2],
                                      const float* __restrict__ bias,
                                      char* bout, char* stats,
                                      int ft0, int w, int sl, int h, int swz) {
    float s[2] = {0.f, 0.f}, ss[2] = {0.f, 0.f};
    #pragma unroll
    for (int j = 0; j < FW; ++j) {
        #pragma unroll
        for (int q = 0; q < 4; ++q) {
            float4 bv = *reinterpret_cast<const float4*>(bias + (ft0 + j) * 32 + q * 8 + h * 4);
            #pragma unroll
            for (int st = 0; st < 2; ++st) {
                float o[4];
                #pragma unroll
                for (int r = 0; r < 4; ++r) {
                    float v = acc[j][st][q * 4 + r] + (&bv.x)[r];
                    o[r] = v;
                    s[st] += v; ss[st] += v * v;
                }
                u32 p0 = (u32)__builtin_bit_cast(u16, (f16)o[0]) | ((u32)__builtin_bit_cast(u16, (f16)o[1]) << 16);
                u32 p1 = (u32)__builtin_bit_cast(u16, (f16)o[2]) | ((u32)__builtin_bit_cast(u16, (f16)o[3]) << 16);
                int byte = (st * 32 + sl) * 1024 + (((ft0 + j) * 64 + q * 16 + h * 8) ^ swz);
                *reinterpret_cast<uint2*>(bout + byte) = make_uint2(p0, p1);
            }
        }
    }
    #pragma unroll
    for (int st = 0; st < 2; ++st) {
        s[st]  += __shfl_xor(s[st], 32);
        ss[st] += __shfl_xor(ss[st], 32);
    }
    if (h == 0) {
        #pragma unroll
        for (int st = 0; st < 2; ++st) {
            *reinterpret_cast<float2*>(stats + ((size_t)w * 64 + st * 32 + sl) * 8) =
                make_float2(s[st], ss[st]);
        }
    }
}

// pass2: cross-wave stats reduce + LN + relu, in place on bout.
// thread (w, lane): samples [w*16, w*16+16), feats [lane*FPL, lane*FPL+FPL)
template<int DOUT>
__device__ __forceinline__ void pass2(char* bout, const char* stats,
                                      const float* __restrict__ lw,
                                      const float* __restrict__ lb,
                                      int w, int lane) {
    constexpr int FPL = DOUT / 64;    // 8 or 4 feats per lane
    const int f0 = lane * FPL;
    float wv[FPL], bv[FPL];
    #pragma unroll
    for (int k = 0; k < FPL; k += 4) {
        float4 a = *reinterpret_cast<const float4*>(lw + f0 + k);
        float4 c = *reinterpret_cast<const float4*>(lb + f0 + k);
        wv[k] = a.x; wv[k+1] = a.y; wv[k+2] = a.z; wv[k+3] = a.w;
        bv[k] = c.x; bv[k+1] = c.y; bv[k+2] = c.z; bv[k+3] = c.w;
    }
    #pragma unroll
    for (int i = 0; i < 16; ++i) {
        int samp = w * 16 + i;
        float S = 0.f, SS = 0.f;
        #pragma unroll
        for (int ww = 0; ww < 4; ++ww) {
            float2 p = *reinterpret_cast<const float2*>(stats + ((size_t)ww * 64 + samp) * 8);
            S += p.x; SS += p.y;
        }
        float mean = S * (1.0f / DOUT);
        float var  = SS * (1.0f / DOUT) - mean * mean;
        float rstd = 1.0f / sqrtf(var + 1e-5f);
        char* p = bout + samp * 1024 + ((f0 * 2) ^ ((samp & 15) << 4));
        if constexpr (FPL == 8) {
            f16x8 x = bc(*reinterpret_cast<const uint4*>(p));
            u32 o[4];
            #pragma unroll
            for (int k = 0; k < 4; ++k) {
                float y0 = fmaxf(wv[2*k]   * (((float)x[2*k])   - mean) * rstd + bv[2*k],   0.f);
                float y1 = fmaxf(wv[2*k+1] * (((float)x[2*k+1]) - mean) * rstd + bv[2*k+1], 0.f);
                o[k] = (u32)__builtin_bit_cast(u16, (f16)y0) | ((u32)__builtin_bit_cast(u16, (f16)y1) << 16);
            }
            *reinterpret_cast<uint4*>(p) = make_uint4(o[0], o[1], o[2], o[3]);
        } else {
            uint2 raw = *reinterpret_cast<const uint2*>(p);
            f16 x[4];
            x[0] = __builtin_bit_cast(f16, (u16)(raw.x & 0xffff));
            x[1] = __builtin_bit_cast(f16, (u16)(raw.x >> 16));
            x[2] = __builtin_bit_cast(f16, (u16)(raw.y & 0xffff));
            x[3] = __builtin_bit_cast(f16, (u16)(raw.y >> 16));
            u32 o[2];
            #pragma unroll
            for (int k = 0; k < 2; ++k) {
                float y0 = fmaxf(wv[2*k]   * (((float)x[2*k])   - mean) * rstd + bv[2*k],   0.f);
                float y1 = fmaxf(wv[2*k+1] * (((float)x[2*k+1]) - mean) * rstd + bv[2*k+1], 0.f);
                o[k] = (u32)__builtin_bit_cast(u16, (f16)y0) | ((u32)__builtin_bit_cast(u16, (f16)y1) << 16);
            }
            *reinterpret_cast<uint2*>(p) = make_uint2(o[0], o[1]);
        }
    }
}

// hidden layer: feature-split MFMA loop (A from global via 2-deep pipeline, B from LDS)
template<int DIN, int DOUT>
__device__ __forceinline__ void hidden(const u16* __restrict__ seg,
                                       const float* __restrict__ bias,
                                       const float* __restrict__ lw,
                                       const float* __restrict__ lb,
                                       char* bin, char* bout, char* stats,
                                       int w, int lane, int h, int sl, int swz) {
    constexpr int KT = DIN / 16, FTT = DOUT / 32, FW = FTT / NW;
    constexpr int AST = FTT * 1024;       // byte stride between kt steps
    const int ft0 = w * FW;
    f32x16 acc[FW][2];
    #pragma unroll
    for (int j = 0; j < FW; ++j) { acc[j][0] = zero16(); acc[j][1] = zero16(); }
    const char* abase = (const char*)seg + (size_t)ft0 * 1024 + lane * 16;
    const char* brow  = bin + sl * 1024 + (h * 16);
    uint4 cur[FW], nxt[FW];
    #pragma unroll
    for (int j = 0; j < FW; ++j) cur[j] = *reinterpret_cast<const uint4*>(abase + j * 1024);
    #pragma unroll
    for (int j = 0; j < FW; ++j) nxt[j] = *reinterpret_cast<const uint4*>(abase + AST + j * 1024);
    #pragma unroll
    for (int kt = 0; kt < KT; ++kt) {
        uint4 pf[FW];
        if (kt + 2 < KT) {
            #pragma unroll
            for (int j = 0; j < FW; ++j)
                pf[j] = *reinterpret_cast<const uint4*>(abase + (size_t)(kt + 2) * AST + j * 1024);
        }
        const char* bl = brow + ((kt * 32) ^ swz);   // ^swz only touches bits 4-7; h*16 pre-added
        f16x8 B0 = bc(*reinterpret_cast<const uint4*>(bin + sl * 1024 + ((kt * 32 + h * 16) ^ swz)));
        f16x8 B1 = bc(*reinterpret_cast<const uint4*>(bin + (32 + sl) * 1024 + ((kt * 32 + h * 16) ^ swz)));
        (void)bl;
        #pragma unroll
        for (int j = 0; j < FW; ++j) {
            f16x8 A = bc(cur[j]);
            acc[j][0] = __builtin_amdgcn_mfma_f32_32x32x16_f16(A, B0, acc[j][0], 0, 0, 0);
            acc[j][1] = __builtin_amdgcn_mfma_f32_32x32x16_f16(A, B1, acc[j][1], 0, 0, 0);
        }
        #pragma unroll
        for (int j = 0; j < FW; ++j) { cur[j] = nxt[j]; nxt[j] = pf[j]; }
    }
    pass1<FW>(acc, bias, bout, stats, ft0, w, sl, h, swz);
    __syncthreads();
    pass2<DOUT>(bout, stats, lw, lb, w, lane);
    __syncthreads();
}

// input layer: K=16 (6 real + pad), B built from registers
template<int DOUT>
__device__ __forceinline__ void layer_in(const u16* __restrict__ seg,
                                         const float* __restrict__ bias,
                                         const float* __restrict__ lw,
                                         const float* __restrict__ lb,
                                         char* bout, char* stats, const f16x8 (&ib)[2],
                                         int w, int lane, int h, int sl, int swz) {
    constexpr int FTT = DOUT / 32, FW = FTT / NW;
    const int ft0 = w * FW;
    f32x16 acc[FW][2];
    #pragma unroll
    for (int j = 0; j < FW; ++j) { acc[j][0] = zero16(); acc[j][1] = zero16(); }
    const char* abase = (const char*)seg + (size_t)ft0 * 1024 + lane * 16;
    #pragma unroll
    for (int j = 0; j < FW; ++j) {
        f16x8 A = bc(*reinterpret_cast<const uint4*>(abase + j * 1024));
        acc[j][0] = __builtin_amdgcn_mfma_f32_32x32x16_f16(A, ib[0], acc[j][0], 0, 0, 0);
        acc[j][1] = __builtin_amdgcn_mfma_f32_32x32x16_f16(A, ib[1], acc[j][1], 0, 0, 0);
    }
    pass1<FW>(acc, bias, bout, stats, ft0, w, sl, h, swz);
    __syncthreads();
    pass2<DOUT>(bout, stats, lw, lb, w, lane);
    __syncthreads();
}

// output layer: 3 features; waves 0,1 each handle one sample-tile
template<int DIN>
__device__ __forceinline__ void layer_out(const u16* __restrict__ seg,
                                          const float* __restrict__ b_out,
                                          const char* bin, float* __restrict__ out,
                                          int F, int samp0, int w, int h, int sl, int swz) {
    if (w < 2) {
        constexpr int KT = DIN / 16;
        f32x16 acc = zero16();
        const char* abase = (const char*)seg + (threadIdx.x & 63) * 16;
        const char* brow  = bin + (w * 32 + sl) * 1024;
        #pragma unroll
        for (int kt = 0; kt < KT; ++kt) {
            f16x8 A = bc(*reinterpret_cast<const uint4*>(abase + kt * 1024));
            f16x8 B = bc(*reinterpret_cast<const uint4*>(brow + ((kt * 32 + h * 16) ^ swz)));
            acc = __builtin_amdgcn_mfma_f32_32x32x16_f16(A, B, acc, 0, 0, 0);
        }
        if (h == 0) {
            float* o = out + (size_t)(samp0 + w * 32 + sl) * 9 + F * 3;
            o[0] = acc[0] + b_out[0];
            o[1] = acc[1] + b_out[1];
            o[2] = acc[2] + b_out[2];
        }
    }
    __syncthreads();
}

template<int F>
__device__ __forceinline__ void run_factor(const float* __restrict__ b_in,
                                           const float* __restrict__ bs,
                                           const float* __restrict__ lnw,
                                           const float* __restrict__ lnb,
                                           const float* __restrict__ b_out,
                                           const u16* __restrict__ wt,
                                           float* __restrict__ out,
                                           char* lds, const f16x8 (&ib)[2],
                                           int samp0, int w, int lane, int h, int sl, int swz) {
    char* b0 = lds;
    char* b1 = lds + LDSB;
    char* stats = lds + STATS_OFF;
    layer_in<wact(F,0)>(wt + (size_t)seg_off(F,0) * 512, b_in, lnw, lnb, b0, stats, ib, w, lane, h, sl, swz);
    hidden<wact(F,0), wact(F,1)>(wt + (size_t)seg_off(F,1) * 512, bs + 0*HID, lnw + 1*HID, lnb + 1*HID, b0, b1, stats, w, lane, h, sl, swz);
    hidden<wact(F,1), wact(F,2)>(wt + (size_t)seg_off(F,2) * 512, bs + 1*HID, lnw + 2*HID, lnb + 2*HID, b1, b0, stats, w, lane, h, sl, swz);
    hidden<wact(F,2), wact(F,3)>(wt + (size_t)seg_off(F,3) * 512, bs + 2*HID, lnw + 3*HID, lnb + 3*HID, b0, b1, stats, w, lane, h, sl, swz);
    hidden<wact(F,3), wact(F,4)>(wt + (size_t)seg_off(F,4) * 512, bs + 3*HID, lnw + 4*HID, lnb + 4*HID, b1, b0, stats, w, lane, h, sl, swz);
    hidden<wact(F,4), wact(F,5)>(wt + (size_t)seg_off(F,5) * 512, bs + 4*HID, lnw + 5*HID, lnb + 5*HID, b0, b1, stats, w, lane, h, sl, swz);
    hidden<wact(F,5), wact(F,6)>(wt + (size_t)seg_off(F,6) * 512, bs + 5*HID, lnw + 6*HID, lnb + 6*HID, b1, b0, stats, w, lane, h, sl, swz);
    layer_out<wact(F,6)>(wt + (size_t)seg_off(F,7) * 512, b_out, b0, out, F, samp0, w, h, sl, swz);
}

__global__ __launch_bounds__(NW * 64, 1) void mipnet_kernel(
        const float* __restrict__ inp, const float* __restrict__ b_in,
        const float* __restrict__ bs, const float* __restrict__ lnw,
        const float* __restrict__ lnb, const float* __restrict__ b_out,
        const u16* __restrict__ wt, float* __restrict__ out) {
    extern __shared__ char lds[];
    const int tid  = threadIdx.x;
    const int w    = tid >> 6;
    const int lane = tid & 63;
    const int h    = lane >> 5;
    const int sl   = lane & 31;
    const int swz  = (sl & 15) << 4;
    const int samp0 = blockIdx.x * BSAMP;

    // build input B-fragments once; reused by all 3 factors (K = 6 padded to 16)
    f16x8 ib[2];
    #pragma unroll
    for (int st = 0; st < 2; ++st) {
        f16x8 B = {(f16)0.f, (f16)0.f, (f16)0.f, (f16)0.f, (f16)0.f, (f16)0.f, (f16)0.f, (f16)0.f};
        if (h == 0) {
            const float* p = inp + (size_t)(samp0 + st * 32 + sl) * 6;
            float2 v0 = *reinterpret_cast<const float2*>(p + 0);
            float2 v1 = *reinterpret_cast<const float2*>(p + 2);
            float2 v2 = *reinterpret_cast<const float2*>(p + 4);
            B[0] = (f16)v0.x; B[1] = (f16)v0.y;
            B[2] = (f16)v1.x; B[3] = (f16)v1.y;
            B[4] = (f16)v2.x; B[5] = (f16)v2.y;
        }
        ib[st] = B;
    }
    run_factor<0>(b_in, bs, lnw, lnb, b_out, wt, out, lds, ib, samp0, w, lane, h, sl, swz);
    run_factor<1>(b_in, bs, lnw, lnb, b_out, wt, out, lds, ib, samp0, w, lane, h, sl, swz);
    run_factor<2>(b_in, bs, lnw, lnb, b_out, wt, out, lds, ib, samp0, w, lane, h, sl, swz);
}

extern "C" void kernel_launch(void* const* d_in, const int* in_sizes, int n_in,
                              void* d_out, int out_size, void* d_ws, size_t ws_size,
                              hipStream_t stream) {
    (void)in_sizes; (void)n_in; (void)out_size; (void)ws_size;
    const float* inputs = (const float*)d_in[0];
    const float* W_in   = (const float*)d_in[1];
    const float* b_in   = (const float*)d_in[2];
    const float* Ws     = (const float*)d_in[3];
    const float* bs     = (const float*)d_in[4];
    const float* lnw    = (const float*)d_in[5];
    const float* lnb    = (const float*)d_in[6];
    const float* W_out  = (const float*)d_in[7];
    const float* b_out  = (const float*)d_in[8];
    u16* wt = (u16*)d_ws;   // TOTAL_TILES*1024 = ~5.5MB of scratch

    hipFuncSetAttribute(reinterpret_cast<const void*>(mipnet_kernel),
                        hipFuncAttributeMaxDynamicSharedMemorySize, LDS_TOTAL);

    prep_kernel<<<TOTAL_TILES, 256, 0, stream>>>(W_in, Ws, W_out, wt);
    mipnet_kernel<<<NSAMP / BSAMP, NW * 64, LDS_TOTAL, stream>>>(
        inputs, b_in, bs, lnw, lnb, b_out, wt, (float*)d_out);
}